// Round 2
// baseline (1392.642 us; speedup 1.0000x reference)
//
#include <hip/hip_runtime.h>
#include <hip/hip_bf16.h>

#define NDIM 256
#define FDIM 32
#define HOPS 4

// ---------- CSR build ----------
__global__ void hist_kernel(const int* __restrict__ dst, int* __restrict__ deg, int E) {
    int e = blockIdx.x * blockDim.x + threadIdx.x;
    if (e < E) atomicAdd(&deg[dst[e]], 1);
}

__global__ void scan_kernel(const int* __restrict__ deg, int* __restrict__ rowptr,
                            int* __restrict__ cursor, int n, int Etot) {
    __shared__ int spart[256];
    int t = threadIdx.x;
    int per = (n + 255) / 256;
    int lo = t * per, hi = lo + per; if (hi > n) hi = n; if (lo > n) lo = n;
    int s = 0;
    for (int i = lo; i < hi; ++i) s += deg[i];
    spart[t] = s;
    __syncthreads();
    if (t == 0) {
        int run = 0;
        for (int i = 0; i < 256; ++i) { int v = spart[i]; spart[i] = run; run += v; }
    }
    __syncthreads();
    int run = spart[t];
    for (int i = lo; i < hi; ++i) {
        rowptr[i] = run; cursor[i] = run; run += deg[i];
    }
    if (t == 0) rowptr[n] = Etot;
}

__global__ void fill_kernel(const int* __restrict__ src, const int* __restrict__ dst,
                            int* __restrict__ cursor, int* __restrict__ col, int E) {
    int e = blockIdx.x * blockDim.x + threadIdx.x;
    if (e < E) {
        int d = dst[e];
        int p = atomicAdd(&cursor[d], 1);
        col[p] = src[e];
    }
}

// ---------- initial projection: h = nodes@W_proj + b_proj + type_emb[types] ----------
__global__ void init_h_kernel(const float* __restrict__ nodes,
                              const int* __restrict__ node_types,
                              const float* __restrict__ type_emb,
                              const float* __restrict__ W_proj,
                              const float* __restrict__ b_proj,
                              float* __restrict__ h, int n) {
    int v = blockIdx.x;
    int t = threadIdx.x;
    __shared__ float sn[FDIM];
    if (t < FDIM) sn[t] = nodes[v * FDIM + t];
    __syncthreads();
    int ty = node_types[v];
    float acc = b_proj[t] + type_emb[ty * NDIM + t];
#pragma unroll
    for (int k = 0; k < FDIM; ++k) acc += sn[k] * W_proj[k * NDIM + t];
    h[(size_t)v * NDIM + t] = acc;
}

// ---------- neighbor sum: S[v] = sum_{e:dst=v} h[src_e] ----------
__global__ __launch_bounds__(256) void agg_kernel(const float* __restrict__ h,
                                                  const int* __restrict__ rowptr,
                                                  const int* __restrict__ col,
                                                  float* __restrict__ S, int n) {
    int wv = threadIdx.x >> 6, lane = threadIdx.x & 63;
    int v = blockIdx.x * 4 + wv;
    if (v >= n) return;
    int beg = rowptr[v], end = rowptr[v + 1];
    float4 acc = make_float4(0.f, 0.f, 0.f, 0.f);
    for (int i = beg; i < end; ++i) {
        int s = col[i];
        float4 x = *(const float4*)&h[(size_t)s * NDIM + lane * 4];
        acc.x += x.x; acc.y += x.y; acc.z += x.z; acc.w += x.w;
    }
    *(float4*)&S[(size_t)v * NDIM + lane * 4] = acc;
}

// ---------- fused GEMM: Out[v] = act([X[v] ; sc*Y[v]] @ B + bm*bias) ----------
// B is [512,256] fp32 row-major. SCALEY: sc = bm = deg[v], else 1. RELU: relu.
#define BM 128
#define BN 64
#define BK 16

template <bool RELU, bool SCALEY>
__global__ __launch_bounds__(256) void gemm_kernel(const float* __restrict__ X,
                                                   const float* __restrict__ Y,
                                                   const int* __restrict__ deg,
                                                   const float* __restrict__ B,
                                                   const float* __restrict__ bias,
                                                   float* __restrict__ Out, int n) {
    __shared__ float As[BK][BM];
    __shared__ float Bs[BK][BN];
    int t = threadIdx.x;
    int row0 = blockIdx.x * BM;
    int n0 = blockIdx.y * BN;

    int ar0 = t >> 2;            // 0..63
    int ak0 = (t & 3) * 4;       // 0,4,8,12
    int tx = t & 15, ty = t >> 4;

    float acc[8][4];
#pragma unroll
    for (int i = 0; i < 8; ++i)
#pragma unroll
        for (int j = 0; j < 4; ++j) acc[i][j] = 0.f;

    for (int k0 = 0; k0 < 2 * NDIM; k0 += BK) {
        const float* P = (k0 < NDIM) ? X : Y;
        int kofs = k0 & (NDIM - 1);
        __syncthreads();
        // stage A (fp32, transposed into LDS)
#pragma unroll
        for (int h2 = 0; h2 < 2; ++h2) {
            int r = ar0 + h2 * 64;
            int row = row0 + r; if (row >= n) row = n - 1;
            float4 v = *(const float4*)&P[(size_t)row * NDIM + kofs + ak0];
            if (SCALEY && k0 >= NDIM) {
                float s = (float)deg[row];
                v.x *= s; v.y *= s; v.z *= s; v.w *= s;
            }
            As[ak0 + 0][r] = v.x; As[ak0 + 1][r] = v.y;
            As[ak0 + 2][r] = v.z; As[ak0 + 3][r] = v.w;
        }
        // stage B
        {
            int kr = t >> 4;          // 0..15
            int c = (t & 15) * 4;     // 0..60
            float4 v = *(const float4*)&B[(size_t)(k0 + kr) * NDIM + n0 + c];
            Bs[kr][c + 0] = v.x; Bs[kr][c + 1] = v.y;
            Bs[kr][c + 2] = v.z; Bs[kr][c + 3] = v.w;
        }
        __syncthreads();
#pragma unroll
        for (int kk = 0; kk < BK; ++kk) {
            float4 a0 = *(const float4*)&As[kk][ty * 8];
            float4 a1 = *(const float4*)&As[kk][ty * 8 + 4];
            float4 b = *(const float4*)&Bs[kk][tx * 4];
            float av[8] = {a0.x, a0.y, a0.z, a0.w, a1.x, a1.y, a1.z, a1.w};
            float bv[4] = {b.x, b.y, b.z, b.w};
#pragma unroll
            for (int i = 0; i < 8; ++i)
#pragma unroll
                for (int j = 0; j < 4; ++j) acc[i][j] += av[i] * bv[j];
        }
    }
    // epilogue
    float bb[4];
#pragma unroll
    for (int j = 0; j < 4; ++j) bb[j] = bias[n0 + tx * 4 + j];
#pragma unroll
    for (int i = 0; i < 8; ++i) {
        int row = row0 + ty * 8 + i;
        if (row < n) {
            float bm = SCALEY ? (float)deg[row] : 1.0f;
            float4 o;
            o.x = acc[i][0] + bm * bb[0];
            o.y = acc[i][1] + bm * bb[1];
            o.z = acc[i][2] + bm * bb[2];
            o.w = acc[i][3] + bm * bb[3];
            if (RELU) {
                o.x = fmaxf(o.x, 0.f); o.y = fmaxf(o.y, 0.f);
                o.z = fmaxf(o.z, 0.f); o.w = fmaxf(o.w, 0.f);
            }
            *(float4*)&Out[(size_t)row * NDIM + n0 + tx * 4] = o;
        }
    }
}

// ---------- column max over nodes ----------
__global__ void colmax_kernel(const float* __restrict__ h, float* __restrict__ partial, int n) {
    int t = threadIdx.x;
    float m = -1e30f;
    for (int v = blockIdx.x; v < n; v += gridDim.x)
        m = fmaxf(m, h[(size_t)v * NDIM + t]);
    partial[blockIdx.x * NDIM + t] = m;
}

__global__ void out_kernel(const float* __restrict__ partial, int nb,
                           const float* __restrict__ W_out,
                           const float* __restrict__ b_out,
                           float* __restrict__ out) {
    __shared__ float ge[NDIM];
    int t = threadIdx.x;
    float m = -1e30f;
    for (int b = 0; b < nb; ++b) m = fmaxf(m, partial[b * NDIM + t]);
    ge[t] = m;
    __syncthreads();
    float acc = b_out[t];
    for (int k = 0; k < NDIM; ++k) acc += ge[k] * W_out[k * NDIM + t];
    out[t] = acc;
}

// ---------- launch ----------
extern "C" void kernel_launch(void* const* d_in, const int* in_sizes, int n_in,
                              void* d_out, int out_size, void* d_ws, size_t ws_size,
                              hipStream_t stream) {
    const float* nodes      = (const float*)d_in[0];
    const int*   edges      = (const int*)d_in[1];
    const int*   node_types = (const int*)d_in[2];
    const float* type_emb   = (const float*)d_in[3];
    const float* W_proj     = (const float*)d_in[4];
    const float* b_proj     = (const float*)d_in[5];
    const float* W_msg      = (const float*)d_in[6];
    const float* b_msg      = (const float*)d_in[7];
    const float* W_upd      = (const float*)d_in[8];
    const float* b_upd      = (const float*)d_in[9];
    const float* W_out      = (const float*)d_in[10];
    const float* b_out      = (const float*)d_in[11];

    int n = in_sizes[2];
    int E = in_sizes[1] / 2;
    const int* src = edges;
    const int* dst = edges + E;

    // workspace layout
    size_t off = 0;
    auto alloc = [&](size_t bytes) {
        void* p = (char*)d_ws + off;
        off += (bytes + 255) & ~(size_t)255;
        return p;
    };
    int* deg    = (int*)alloc((size_t)n * 4);
    int* rowptr = (int*)alloc((size_t)(n + 1) * 4);
    int* cursor = (int*)alloc((size_t)n * 4);
    int* col    = (int*)alloc((size_t)E * 4);
    float* hA   = (float*)alloc((size_t)n * NDIM * 4);
    float* hB   = (float*)alloc((size_t)n * NDIM * 4);
    float* hC   = (float*)alloc((size_t)n * NDIM * 4);
    float* partial = (float*)alloc((size_t)256 * NDIM * 4);

    hipMemsetAsync(deg, 0, (size_t)n * 4, stream);
    int eb = (E + 255) / 256;
    hist_kernel<<<eb, 256, 0, stream>>>(dst, deg, E);
    scan_kernel<<<1, 256, 0, stream>>>(deg, rowptr, cursor, n, E);
    fill_kernel<<<eb, 256, 0, stream>>>(src, dst, cursor, col, E);
    init_h_kernel<<<n, 256, 0, stream>>>(nodes, node_types, type_emb, W_proj, b_proj, hA, n);

    float* h  = hA;
    float* Sb = hB;
    float* Ab = hC;
    int gx = (n + BM - 1) / BM;
    dim3 ggrid(gx, NDIM / BN);
    for (int i = 0; i < HOPS; ++i) {
        agg_kernel<<<(n + 3) / 4, 256, 0, stream>>>(h, rowptr, col, Sb, n);
        gemm_kernel<false, true><<<ggrid, 256, 0, stream>>>(
            Sb, h, deg, W_msg + (size_t)i * 2 * NDIM * NDIM, b_msg + (size_t)i * NDIM, Ab, n);
        gemm_kernel<true, false><<<ggrid, 256, 0, stream>>>(
            h, Ab, deg, W_upd + (size_t)i * 2 * NDIM * NDIM, b_upd + (size_t)i * NDIM, Sb, n);
        float* tmp = h; h = Sb; Sb = tmp;
    }
    colmax_kernel<<<256, 256, 0, stream>>>(h, partial, n);
    out_kernel<<<1, 256, 0, stream>>>(partial, 256, W_out, b_out, (float*)d_out);
}

// Round 3
// 690.468 us; speedup vs baseline: 2.0170x; 2.0170x over previous
//
#include <hip/hip_runtime.h>
#include <hip/hip_bf16.h>

#define NDIM 256
#define FDIM 32
#define HOPS 4

typedef __attribute__((ext_vector_type(8))) short short8;
typedef __attribute__((ext_vector_type(4))) float f32x4;

// ---------- helpers ----------
__device__ inline float b2f(unsigned short u) {
    union { unsigned int i; float f; } v; v.i = ((unsigned int)u) << 16; return v.f;
}
__device__ inline unsigned short f2b(float f) {
    union { float f; unsigned int i; } v; v.f = f;
    unsigned int r = v.i + 0x7FFF + ((v.i >> 16) & 1);
    return (unsigned short)(r >> 16);
}

// ---------- CSR build ----------
__global__ void hist_kernel(const int* __restrict__ dst, int* __restrict__ deg, int E) {
    int e = blockIdx.x * blockDim.x + threadIdx.x;
    if (e < E) atomicAdd(&deg[dst[e]], 1);
}

__global__ void scan_kernel(const int* __restrict__ deg, int* __restrict__ rowptr,
                            int* __restrict__ cursor, int n, int Etot) {
    __shared__ int spart[256];
    int t = threadIdx.x;
    int per = (n + 255) / 256;
    int lo = t * per, hi = lo + per; if (hi > n) hi = n; if (lo > n) lo = n;
    int s = 0;
    for (int i = lo; i < hi; ++i) s += deg[i];
    spart[t] = s;
    __syncthreads();
    if (t == 0) {
        int run = 0;
        for (int i = 0; i < 256; ++i) { int v = spart[i]; spart[i] = run; run += v; }
    }
    __syncthreads();
    int run = spart[t];
    for (int i = lo; i < hi; ++i) {
        rowptr[i] = run; cursor[i] = run; run += deg[i];
    }
    if (t == 0) rowptr[n] = Etot;
}

__global__ void fill_kernel(const int* __restrict__ src, const int* __restrict__ dst,
                            int* __restrict__ cursor, int* __restrict__ col, int E) {
    int e = blockIdx.x * blockDim.x + threadIdx.x;
    if (e < E) {
        int d = dst[e];
        int p = atomicAdd(&cursor[d], 1);
        col[p] = src[e];
    }
}

// ---------- weight transpose+convert: W[512][256] fp32 -> Wt[256][512] bf16 ----------
__global__ __launch_bounds__(256) void wtrans_kernel(const float* __restrict__ Wm,
                                                     const float* __restrict__ Wu,
                                                     unsigned short* __restrict__ WtM,
                                                     unsigned short* __restrict__ WtU) {
    int mat = blockIdx.z;
    const float* src = (mat < HOPS) ? (Wm + (size_t)mat * 512 * 256)
                                    : (Wu + (size_t)(mat - HOPS) * 512 * 256);
    unsigned short* dstp = (mat < HOPS) ? (WtM + (size_t)mat * 256 * 512)
                                        : (WtU + (size_t)(mat - HOPS) * 256 * 512);
    int k0 = blockIdx.x * 32, n0 = blockIdx.y * 32;
    __shared__ float T[32][33];
    int tr = threadIdx.x >> 5, tc = threadIdx.x & 31;
#pragma unroll
    for (int r = 0; r < 4; ++r) {
        int k = tr + r * 8;
        T[tc][k] = src[(size_t)(k0 + k) * 256 + n0 + tc];
    }
    __syncthreads();
#pragma unroll
    for (int r = 0; r < 4; ++r) {
        int nn = tr + r * 8;
        dstp[(size_t)(n0 + nn) * 512 + k0 + tc] = f2b(T[nn][tc]);
    }
}

// ---------- initial projection: h = nodes@W_proj + b_proj + type_emb[types] (bf16 out) ----------
__global__ void init_h_kernel(const float* __restrict__ nodes,
                              const int* __restrict__ node_types,
                              const float* __restrict__ type_emb,
                              const float* __restrict__ W_proj,
                              const float* __restrict__ b_proj,
                              unsigned short* __restrict__ h, int n) {
    int v = blockIdx.x;
    int t = threadIdx.x;
    __shared__ float sn[FDIM];
    if (t < FDIM) sn[t] = nodes[v * FDIM + t];
    __syncthreads();
    int ty = node_types[v];
    float acc = b_proj[t] + type_emb[ty * NDIM + t];
#pragma unroll
    for (int k = 0; k < FDIM; ++k) acc += sn[k] * W_proj[k * NDIM + t];
    h[(size_t)v * NDIM + t] = f2b(acc);
}

// ---------- neighbor sum: S[v] = sum_{e:dst=v} h[src_e]  (bf16 in/out, fp32 acc) ----------
__global__ __launch_bounds__(256) void agg_kernel(const unsigned short* __restrict__ h,
                                                  const int* __restrict__ rowptr,
                                                  const int* __restrict__ col,
                                                  unsigned short* __restrict__ S, int n) {
    int wv = threadIdx.x >> 6, lane = threadIdx.x & 63;
    int v = blockIdx.x * 4 + wv;
    if (v >= n) return;
    int beg = rowptr[v], end = rowptr[v + 1];
    float a0 = 0.f, a1 = 0.f, a2 = 0.f, a3 = 0.f;
    for (int i = beg; i < end; ++i) {
        int s = col[i];
        ushort4 x = *(const ushort4*)&h[(size_t)s * NDIM + lane * 4];
        a0 += b2f(x.x); a1 += b2f(x.y); a2 += b2f(x.z); a3 += b2f(x.w);
    }
    ushort4 o; o.x = f2b(a0); o.y = f2b(a1); o.z = f2b(a2); o.w = f2b(a3);
    *(ushort4*)&S[(size_t)v * NDIM + lane * 4] = o;
}

// ---------- MFMA GEMM: Out[v] = act([X[v] ; sc*Y[v]] @ Wt^T + bm*bias) (bf16 out) ----------
// Wt is [256][512] bf16 (pre-transposed). SCALEY: sc=bm=deg[v]. RELU optional.
#define BM 128
#define BN 128
#define BK 32
#define ASTR (BK + 8)   // 40 shorts -> 80B row stride, 16B aligned, 2-way bank alias only

template <bool RELU, bool SCALEY>
__global__ __launch_bounds__(256) void gemm_kernel(const unsigned short* __restrict__ X,
                                                   const unsigned short* __restrict__ Y,
                                                   const int* __restrict__ deg,
                                                   const unsigned short* __restrict__ Wt,
                                                   const float* __restrict__ bias,
                                                   unsigned short* __restrict__ Out, int n) {
    __shared__ unsigned short As[BM][ASTR];
    __shared__ unsigned short Bs[BN][ASTR];
    int t = threadIdx.x;
    int lane = t & 63;
    int w = t >> 6;
    int wm = w >> 1, wn = w & 1;
    int quad = lane >> 4, l16 = lane & 15;
    int row0 = blockIdx.x * BM;
    int n0 = blockIdx.y * BN;

    f32x4 acc[4][4];
#pragma unroll
    for (int i = 0; i < 4; ++i)
#pragma unroll
        for (int j = 0; j < 4; ++j) acc[i][j] = (f32x4)(0.f);

    for (int k0 = 0; k0 < 2 * NDIM; k0 += BK) {
        const unsigned short* P = (k0 < NDIM) ? X : Y;
        int kofs = k0 & (NDIM - 1);
        __syncthreads();
        // stage A: 128 rows x 32 shorts; each thread 2 x 16B chunks
#pragma unroll
        for (int h2 = 0; h2 < 2; ++h2) {
            int c = t + h2 * 256;
            int r = c >> 2;
            int ko = (c & 3) * 8;
            int grow = row0 + r; if (grow >= n) grow = n - 1;
            uint4 u = *(const uint4*)(P + (size_t)grow * NDIM + kofs + ko);
            if (SCALEY && k0 >= NDIM) {
                float s = (float)deg[grow];
                unsigned short* up = (unsigned short*)&u;
#pragma unroll
                for (int j = 0; j < 8; ++j) up[j] = f2b(b2f(up[j]) * s);
            }
            *(uint4*)&As[r][ko] = u;
        }
        // stage B: 128 n-rows x 32 shorts of Wt[n][k0..]
#pragma unroll
        for (int h2 = 0; h2 < 2; ++h2) {
            int c = t + h2 * 256;
            int r = c >> 2;
            int ko = (c & 3) * 8;
            uint4 u = *(const uint4*)(Wt + (size_t)(n0 + r) * 512 + k0 + ko);
            *(uint4*)&Bs[r][ko] = u;
        }
        __syncthreads();
        short8 af[4], bf[4];
#pragma unroll
        for (int mt = 0; mt < 4; ++mt)
            af[mt] = *(const short8*)&As[wm * 64 + mt * 16 + l16][quad * 8];
#pragma unroll
        for (int nt = 0; nt < 4; ++nt)
            bf[nt] = *(const short8*)&Bs[wn * 64 + nt * 16 + l16][quad * 8];
#pragma unroll
        for (int mt = 0; mt < 4; ++mt)
#pragma unroll
            for (int nt = 0; nt < 4; ++nt)
                acc[mt][nt] = __builtin_amdgcn_mfma_f32_16x16x32_bf16(af[mt], bf[nt], acc[mt][nt], 0, 0, 0);
    }
    // epilogue: C/D layout col=lane&15, row=quad*4+reg
#pragma unroll
    for (int mt = 0; mt < 4; ++mt) {
#pragma unroll
        for (int nt = 0; nt < 4; ++nt) {
            int col = n0 + wn * 64 + nt * 16 + l16;
            float bcol = bias[col];
#pragma unroll
            for (int r = 0; r < 4; ++r) {
                int row = row0 + wm * 64 + mt * 16 + quad * 4 + r;
                if (row < n) {
                    float bm = SCALEY ? (float)deg[row] : 1.0f;
                    float v = acc[mt][nt][r] + bm * bcol;
                    if (RELU) v = fmaxf(v, 0.f);
                    Out[(size_t)row * NDIM + col] = f2b(v);
                }
            }
        }
    }
}

// ---------- column max over nodes (bf16 in, fp32 partial) ----------
__global__ void colmax_kernel(const unsigned short* __restrict__ h,
                              float* __restrict__ partial, int n) {
    int t = threadIdx.x;
    float m = -1e30f;
    for (int v = blockIdx.x; v < n; v += gridDim.x)
        m = fmaxf(m, b2f(h[(size_t)v * NDIM + t]));
    partial[blockIdx.x * NDIM + t] = m;
}

__global__ void out_kernel(const float* __restrict__ partial, int nb,
                           const float* __restrict__ W_out,
                           const float* __restrict__ b_out,
                           float* __restrict__ out) {
    __shared__ float ge[NDIM];
    int t = threadIdx.x;
    float m = -1e30f;
    for (int b = 0; b < nb; ++b) m = fmaxf(m, partial[b * NDIM + t]);
    ge[t] = m;
    __syncthreads();
    float acc = b_out[t];
    for (int k = 0; k < NDIM; ++k) acc += ge[k] * W_out[k * NDIM + t];
    out[t] = acc;
}

// ---------- launch ----------
extern "C" void kernel_launch(void* const* d_in, const int* in_sizes, int n_in,
                              void* d_out, int out_size, void* d_ws, size_t ws_size,
                              hipStream_t stream) {
    const float* nodes      = (const float*)d_in[0];
    const int*   edges      = (const int*)d_in[1];
    const int*   node_types = (const int*)d_in[2];
    const float* type_emb   = (const float*)d_in[3];
    const float* W_proj     = (const float*)d_in[4];
    const float* b_proj     = (const float*)d_in[5];
    const float* W_msg      = (const float*)d_in[6];
    const float* b_msg      = (const float*)d_in[7];
    const float* W_upd      = (const float*)d_in[8];
    const float* b_upd      = (const float*)d_in[9];
    const float* W_out      = (const float*)d_in[10];
    const float* b_out      = (const float*)d_in[11];

    int n = in_sizes[2];
    int E = in_sizes[1] / 2;
    const int* src = edges;
    const int* dst = edges + E;

    size_t off = 0;
    auto alloc = [&](size_t bytes) {
        void* p = (char*)d_ws + off;
        off += (bytes + 255) & ~(size_t)255;
        return p;
    };
    int* deg    = (int*)alloc((size_t)n * 4);
    int* rowptr = (int*)alloc((size_t)(n + 1) * 4);
    int* cursor = (int*)alloc((size_t)n * 4);
    int* col    = (int*)alloc((size_t)E * 4);
    unsigned short* WtM = (unsigned short*)alloc((size_t)HOPS * 256 * 512 * 2);
    unsigned short* WtU = (unsigned short*)alloc((size_t)HOPS * 256 * 512 * 2);
    unsigned short* hA  = (unsigned short*)alloc((size_t)n * NDIM * 2);
    unsigned short* hB  = (unsigned short*)alloc((size_t)n * NDIM * 2);
    unsigned short* hC  = (unsigned short*)alloc((size_t)n * NDIM * 2);
    float* partial = (float*)alloc((size_t)256 * NDIM * 4);

    hipMemsetAsync(deg, 0, (size_t)n * 4, stream);
    int eb = (E + 255) / 256;
    hist_kernel<<<eb, 256, 0, stream>>>(dst, deg, E);
    scan_kernel<<<1, 256, 0, stream>>>(deg, rowptr, cursor, n, E);
    fill_kernel<<<eb, 256, 0, stream>>>(src, dst, cursor, col, E);
    dim3 wg(512 / 32, 256 / 32, 2 * HOPS);
    wtrans_kernel<<<wg, 256, 0, stream>>>(W_msg, W_upd, WtM, WtU);
    init_h_kernel<<<n, 256, 0, stream>>>(nodes, node_types, type_emb, W_proj, b_proj, hA, n);

    unsigned short* h  = hA;
    unsigned short* Sb = hB;
    unsigned short* Ab = hC;
    int gx = (n + BM - 1) / BM;
    dim3 ggrid(gx, NDIM / BN);
    for (int i = 0; i < HOPS; ++i) {
        agg_kernel<<<(n + 3) / 4, 256, 0, stream>>>(h, rowptr, col, Sb, n);
        gemm_kernel<false, true><<<ggrid, 256, 0, stream>>>(
            Sb, h, deg, WtM + (size_t)i * 256 * 512, b_msg + (size_t)i * NDIM, Ab, n);
        gemm_kernel<true, false><<<ggrid, 256, 0, stream>>>(
            h, Ab, deg, WtU + (size_t)i * 256 * 512, b_upd + (size_t)i * NDIM, Sb, n);
        unsigned short* tmp = h; h = Sb; Sb = tmp;
    }
    colmax_kernel<<<256, 256, 0, stream>>>(h, partial, n);
    out_kernel<<<1, 256, 0, stream>>>(partial, 256, W_out, b_out, (float*)d_out);
}

// Round 4
// 600.670 us; speedup vs baseline: 2.3185x; 1.1495x over previous
//
#include <hip/hip_runtime.h>
#include <hip/hip_bf16.h>

#define NDIM 256
#define FDIM 32
#define HOPS 4

typedef __attribute__((ext_vector_type(8))) short short8;
typedef __attribute__((ext_vector_type(4))) float f32x4;

// ---------- helpers ----------
__device__ inline float b2f(unsigned short u) {
    union { unsigned int i; float f; } v; v.i = ((unsigned int)u) << 16; return v.f;
}
__device__ inline unsigned short f2b(float f) {
    union { float f; unsigned int i; } v; v.f = f;
    unsigned int r = v.i + 0x7FFF + ((v.i >> 16) & 1);
    return (unsigned short)(r >> 16);
}

// ---------- CSR build ----------
__global__ void hist_kernel(const int* __restrict__ dst, int* __restrict__ deg, int E) {
    int e = blockIdx.x * blockDim.x + threadIdx.x;
    if (e < E) atomicAdd(&deg[dst[e]], 1);
}

// 1024-thread two-level shuffle scan over n elements (n ~ 25000)
__global__ __launch_bounds__(1024) void scan_kernel(const int* __restrict__ deg,
                                                    int* __restrict__ rowptr,
                                                    int* __restrict__ cursor, int n, int Etot) {
    __shared__ int wsum[16];
    int t = threadIdx.x;
    int per = (n + 1023) / 1024;
    int lo = t * per; if (lo > n) lo = n;
    int hi = lo + per; if (hi > n) hi = n;
    int s = 0;
    for (int i = lo; i < hi; ++i) s += deg[i];
    int lane = t & 63, wid = t >> 6;
    // inclusive wave scan of s
    int v = s;
#pragma unroll
    for (int d = 1; d < 64; d <<= 1) {
        int u = __shfl_up(v, d, 64);
        if (lane >= d) v += u;
    }
    if (lane == 63) wsum[wid] = v;
    __syncthreads();
    if (wid == 0) {
        int ws = (lane < 16) ? wsum[lane] : 0;
#pragma unroll
        for (int d = 1; d < 16; d <<= 1) {
            int u = __shfl_up(ws, d, 64);
            if (lane >= d) ws += u;
        }
        if (lane < 16) wsum[lane] = ws;
    }
    __syncthreads();
    int base = (wid > 0 ? wsum[wid - 1] : 0) + (v - s);  // exclusive offset
    int run = base;
    for (int i = lo; i < hi; ++i) {
        rowptr[i] = run; cursor[i] = run; run += deg[i];
    }
    if (t == 0) rowptr[n] = Etot;
}

__global__ void fill_kernel(const int* __restrict__ src, const int* __restrict__ dst,
                            int* __restrict__ cursor, int* __restrict__ col, int E) {
    int e = blockIdx.x * blockDim.x + threadIdx.x;
    if (e < E) {
        int d = dst[e];
        int p = atomicAdd(&cursor[d], 1);
        col[p] = src[e];
    }
}

// ---------- weight transpose+convert: W[512][256] fp32 -> Wt[256][512] bf16 ----------
__global__ __launch_bounds__(256) void wtrans_kernel(const float* __restrict__ Wm,
                                                     const float* __restrict__ Wu,
                                                     unsigned short* __restrict__ WtM,
                                                     unsigned short* __restrict__ WtU) {
    int mat = blockIdx.z;
    const float* src = (mat < HOPS) ? (Wm + (size_t)mat * 512 * 256)
                                    : (Wu + (size_t)(mat - HOPS) * 512 * 256);
    unsigned short* dstp = (mat < HOPS) ? (WtM + (size_t)mat * 256 * 512)
                                        : (WtU + (size_t)(mat - HOPS) * 256 * 512);
    int k0 = blockIdx.x * 32, n0 = blockIdx.y * 32;
    __shared__ float T[32][33];
    int tr = threadIdx.x >> 5, tc = threadIdx.x & 31;
#pragma unroll
    for (int r = 0; r < 4; ++r) {
        int k = tr + r * 8;
        T[tc][k] = src[(size_t)(k0 + k) * 256 + n0 + tc];
    }
    __syncthreads();
#pragma unroll
    for (int r = 0; r < 4; ++r) {
        int nn = tr + r * 8;
        dstp[(size_t)(n0 + nn) * 512 + k0 + tc] = f2b(T[nn][tc]);
    }
}

// ---------- initial projection ----------
__global__ void init_h_kernel(const float* __restrict__ nodes,
                              const int* __restrict__ node_types,
                              const float* __restrict__ type_emb,
                              const float* __restrict__ W_proj,
                              const float* __restrict__ b_proj,
                              unsigned short* __restrict__ h, int n) {
    int v = blockIdx.x;
    int t = threadIdx.x;
    __shared__ float sn[FDIM];
    if (t < FDIM) sn[t] = nodes[v * FDIM + t];
    __syncthreads();
    int ty = node_types[v];
    float acc = b_proj[t] + type_emb[ty * NDIM + t];
#pragma unroll
    for (int k = 0; k < FDIM; ++k) acc += sn[k] * W_proj[k * NDIM + t];
    h[(size_t)v * NDIM + t] = f2b(acc);
}

// ---------- neighbor sum: S[v] = sum_{e:dst=v} h[src_e]  (bf16 in/out, fp32 acc) ----------
__global__ __launch_bounds__(256) void agg_kernel(const unsigned short* __restrict__ h,
                                                  const int* __restrict__ rowptr,
                                                  const int* __restrict__ col,
                                                  unsigned short* __restrict__ S, int n) {
    int wv = threadIdx.x >> 6, lane = threadIdx.x & 63;
    int v = blockIdx.x * 4 + wv;
    if (v >= n) return;
    int beg = rowptr[v], end = rowptr[v + 1];
    float a0 = 0.f, a1 = 0.f, a2 = 0.f, a3 = 0.f;
    size_t lofs = (size_t)lane * 4;
    int i = beg;
    for (; i + 4 <= end; i += 4) {
        int c0 = col[i], c1 = col[i + 1], c2 = col[i + 2], c3 = col[i + 3];
        ushort4 x0 = *(const ushort4*)&h[(size_t)c0 * NDIM + lofs];
        ushort4 x1 = *(const ushort4*)&h[(size_t)c1 * NDIM + lofs];
        ushort4 x2 = *(const ushort4*)&h[(size_t)c2 * NDIM + lofs];
        ushort4 x3 = *(const ushort4*)&h[(size_t)c3 * NDIM + lofs];
        a0 += b2f(x0.x) + b2f(x1.x) + b2f(x2.x) + b2f(x3.x);
        a1 += b2f(x0.y) + b2f(x1.y) + b2f(x2.y) + b2f(x3.y);
        a2 += b2f(x0.z) + b2f(x1.z) + b2f(x2.z) + b2f(x3.z);
        a3 += b2f(x0.w) + b2f(x1.w) + b2f(x2.w) + b2f(x3.w);
    }
    for (; i < end; ++i) {
        int c = col[i];
        ushort4 x = *(const ushort4*)&h[(size_t)c * NDIM + lofs];
        a0 += b2f(x.x); a1 += b2f(x.y); a2 += b2f(x.z); a3 += b2f(x.w);
    }
    ushort4 o; o.x = f2b(a0); o.y = f2b(a1); o.z = f2b(a2); o.w = f2b(a3);
    *(ushort4*)&S[(size_t)v * NDIM + lofs] = o;
}

// ---------- MFMA GEMM: Out[v] = act([X[v] ; sc*Y[v]] @ Wt^T + bm*bias) (bf16 out) ----------
#define BM 128
#define BN 128
#define BK 32
#define ASTR (BK + 8)   // 40 shorts: 80B row stride -> 2-way bank alias only (free)

template <bool RELU, bool SCALEY>
__global__ __launch_bounds__(256) void gemm_kernel(const unsigned short* __restrict__ X,
                                                   const unsigned short* __restrict__ Y,
                                                   const int* __restrict__ deg,
                                                   const unsigned short* __restrict__ Wt,
                                                   const float* __restrict__ bias,
                                                   unsigned short* __restrict__ Out, int n) {
    __shared__ unsigned short As[BM][ASTR];
    __shared__ unsigned short Bs[BN][ASTR];
    int t = threadIdx.x;
    int lane = t & 63;
    int w = t >> 6;
    int wm = w >> 1, wn = w & 1;
    int quad = lane >> 4, l16 = lane & 15;
    int row0 = blockIdx.x * BM;
    int n0 = blockIdx.y * BN;

    f32x4 acc[4][4];
#pragma unroll
    for (int i = 0; i < 4; ++i)
#pragma unroll
        for (int j = 0; j < 4; ++j) acc[i][j] = (f32x4)(0.f);

    for (int k0 = 0; k0 < 2 * NDIM; k0 += BK) {
        const unsigned short* P = (k0 < NDIM) ? X : Y;
        int kofs = k0 & (NDIM - 1);
        __syncthreads();
#pragma unroll
        for (int h2 = 0; h2 < 2; ++h2) {
            int c = t + h2 * 256;
            int r = c >> 2;
            int ko = (c & 3) * 8;
            int grow = row0 + r; if (grow >= n) grow = n - 1;
            uint4 u = *(const uint4*)(P + (size_t)grow * NDIM + kofs + ko);
            if (SCALEY && k0 >= NDIM) {
                float s = (float)deg[grow];
                unsigned short* up = (unsigned short*)&u;
#pragma unroll
                for (int j = 0; j < 8; ++j) up[j] = f2b(b2f(up[j]) * s);
            }
            *(uint4*)&As[r][ko] = u;
        }
#pragma unroll
        for (int h2 = 0; h2 < 2; ++h2) {
            int c = t + h2 * 256;
            int r = c >> 2;
            int ko = (c & 3) * 8;
            uint4 u = *(const uint4*)(Wt + (size_t)(n0 + r) * 512 + k0 + ko);
            *(uint4*)&Bs[r][ko] = u;
        }
        __syncthreads();
        short8 af[4], bf[4];
#pragma unroll
        for (int mt = 0; mt < 4; ++mt)
            af[mt] = *(const short8*)&As[wm * 64 + mt * 16 + l16][quad * 8];
#pragma unroll
        for (int nt = 0; nt < 4; ++nt)
            bf[nt] = *(const short8*)&Bs[wn * 64 + nt * 16 + l16][quad * 8];
#pragma unroll
        for (int mt = 0; mt < 4; ++mt)
#pragma unroll
            for (int nt = 0; nt < 4; ++nt)
                acc[mt][nt] = __builtin_amdgcn_mfma_f32_16x16x32_bf16(af[mt], bf[nt], acc[mt][nt], 0, 0, 0);
    }
    // epilogue: C/D layout col=lane&15, row=quad*4+reg
#pragma unroll
    for (int mt = 0; mt < 4; ++mt) {
#pragma unroll
        for (int nt = 0; nt < 4; ++nt) {
            int col = n0 + wn * 64 + nt * 16 + l16;
            float bcol = bias[col];
#pragma unroll
            for (int r = 0; r < 4; ++r) {
                int row = row0 + wm * 64 + mt * 16 + quad * 4 + r;
                if (row < n) {
                    float bm = SCALEY ? (float)deg[row] : 1.0f;
                    float v = acc[mt][nt][r] + bm * bcol;
                    if (RELU) v = fmaxf(v, 0.f);
                    Out[(size_t)row * NDIM + col] = f2b(v);
                }
            }
        }
    }
}

// ---------- column max over nodes ----------
__global__ void colmax_kernel(const unsigned short* __restrict__ h,
                              float* __restrict__ partial, int n) {
    int t = threadIdx.x;
    float m = -1e30f;
    for (int v = blockIdx.x; v < n; v += gridDim.x)
        m = fmaxf(m, b2f(h[(size_t)v * NDIM + t]));
    partial[blockIdx.x * NDIM + t] = m;
}

__global__ void out_kernel(const float* __restrict__ partial, int nb,
                           const float* __restrict__ W_out,
                           const float* __restrict__ b_out,
                           float* __restrict__ out) {
    __shared__ float ge[NDIM];
    int t = threadIdx.x;
    float m = -1e30f;
    for (int b = 0; b < nb; ++b) m = fmaxf(m, partial[b * NDIM + t]);
    ge[t] = m;
    __syncthreads();
    float acc = b_out[t];
    for (int k = 0; k < NDIM; ++k) acc += ge[k] * W_out[k * NDIM + t];
    out[t] = acc;
}

// ---------- launch ----------
extern "C" void kernel_launch(void* const* d_in, const int* in_sizes, int n_in,
                              void* d_out, int out_size, void* d_ws, size_t ws_size,
                              hipStream_t stream) {
    const float* nodes      = (const float*)d_in[0];
    const int*   edges      = (const int*)d_in[1];
    const int*   node_types = (const int*)d_in[2];
    const float* type_emb   = (const float*)d_in[3];
    const float* W_proj     = (const float*)d_in[4];
    const float* b_proj     = (const float*)d_in[5];
    const float* W_msg      = (const float*)d_in[6];
    const float* b_msg      = (const float*)d_in[7];
    const float* W_upd      = (const float*)d_in[8];
    const float* b_upd      = (const float*)d_in[9];
    const float* W_out      = (const float*)d_in[10];
    const float* b_out      = (const float*)d_in[11];

    int n = in_sizes[2];
    int E = in_sizes[1] / 2;
    const int* src = edges;
    const int* dst = edges + E;

    size_t off = 0;
    auto alloc = [&](size_t bytes) {
        void* p = (char*)d_ws + off;
        off += (bytes + 255) & ~(size_t)255;
        return p;
    };
    int* deg    = (int*)alloc((size_t)n * 4);
    int* rowptr = (int*)alloc((size_t)(n + 1) * 4);
    int* cursor = (int*)alloc((size_t)n * 4);
    int* col    = (int*)alloc((size_t)E * 4);
    unsigned short* WtM = (unsigned short*)alloc((size_t)HOPS * 256 * 512 * 2);
    unsigned short* WtU = (unsigned short*)alloc((size_t)HOPS * 256 * 512 * 2);
    unsigned short* hA  = (unsigned short*)alloc((size_t)n * NDIM * 2);
    unsigned short* hB  = (unsigned short*)alloc((size_t)n * NDIM * 2);
    unsigned short* hC  = (unsigned short*)alloc((size_t)n * NDIM * 2);
    float* partial = (float*)alloc((size_t)256 * NDIM * 4);

    hipMemsetAsync(deg, 0, (size_t)n * 4, stream);
    int eb = (E + 255) / 256;
    hist_kernel<<<eb, 256, 0, stream>>>(dst, deg, E);
    scan_kernel<<<1, 1024, 0, stream>>>(deg, rowptr, cursor, n, E);
    fill_kernel<<<eb, 256, 0, stream>>>(src, dst, cursor, col, E);
    dim3 wg(512 / 32, 256 / 32, 2 * HOPS);
    wtrans_kernel<<<wg, 256, 0, stream>>>(W_msg, W_upd, WtM, WtU);
    init_h_kernel<<<n, 256, 0, stream>>>(nodes, node_types, type_emb, W_proj, b_proj, hA, n);

    unsigned short* h  = hA;
    unsigned short* Sb = hB;
    unsigned short* Ab = hC;
    int gx = (n + BM - 1) / BM;
    dim3 ggrid(gx, NDIM / BN);
    for (int i = 0; i < HOPS; ++i) {
        agg_kernel<<<(n + 3) / 4, 256, 0, stream>>>(h, rowptr, col, Sb, n);
        gemm_kernel<false, true><<<ggrid, 256, 0, stream>>>(
            Sb, h, deg, WtM + (size_t)i * 256 * 512, b_msg + (size_t)i * NDIM, Ab, n);
        gemm_kernel<true, false><<<ggrid, 256, 0, stream>>>(
            h, Ab, deg, WtU + (size_t)i * 256 * 512, b_upd + (size_t)i * NDIM, Sb, n);
        unsigned short* tmp = h; h = Sb; Sb = tmp;
    }
    colmax_kernel<<<256, 256, 0, stream>>>(h, partial, n);
    out_kernel<<<1, 256, 0, stream>>>(partial, 256, W_out, b_out, (float*)d_out);
}

// Round 5
// 551.608 us; speedup vs baseline: 2.5247x; 1.0889x over previous
//
#include <hip/hip_runtime.h>
#include <hip/hip_bf16.h>

#define NDIM 256
#define FDIM 32
#define HOPS 4

typedef __attribute__((ext_vector_type(8))) short short8;
typedef __attribute__((ext_vector_type(4))) float f32x4;

// ---------- helpers ----------
__device__ inline float b2f(unsigned short u) {
    union { unsigned int i; float f; } v; v.i = ((unsigned int)u) << 16; return v.f;
}
__device__ inline unsigned short f2b(float f) {
    union { float f; unsigned int i; } v; v.f = f;
    unsigned int r = v.i + 0x7FFF + ((v.i >> 16) & 1);
    return (unsigned short)(r >> 16);
}

// ---------- CSR build ----------
__global__ void hist_kernel(const int* __restrict__ dst, int* __restrict__ deg, int E) {
    int e = blockIdx.x * blockDim.x + threadIdx.x;
    if (e < E) atomicAdd(&deg[dst[e]], 1);
}

// 1024-thread two-level shuffle scan
__global__ __launch_bounds__(1024) void scan_kernel(const int* __restrict__ deg,
                                                    int* __restrict__ rowptr,
                                                    int* __restrict__ cursor, int n, int Etot) {
    __shared__ int wsum[16];
    int t = threadIdx.x;
    int per = (n + 1023) / 1024;
    int lo = t * per; if (lo > n) lo = n;
    int hi = lo + per; if (hi > n) hi = n;
    int s = 0;
    for (int i = lo; i < hi; ++i) s += deg[i];
    int lane = t & 63, wid = t >> 6;
    int v = s;
#pragma unroll
    for (int d = 1; d < 64; d <<= 1) {
        int u = __shfl_up(v, d, 64);
        if (lane >= d) v += u;
    }
    if (lane == 63) wsum[wid] = v;
    __syncthreads();
    if (wid == 0) {
        int ws = (lane < 16) ? wsum[lane] : 0;
#pragma unroll
        for (int d = 1; d < 16; d <<= 1) {
            int u = __shfl_up(ws, d, 64);
            if (lane >= d) ws += u;
        }
        if (lane < 16) wsum[lane] = ws;
    }
    __syncthreads();
    int base = (wid > 0 ? wsum[wid - 1] : 0) + (v - s);
    int run = base;
    for (int i = lo; i < hi; ++i) {
        rowptr[i] = run; cursor[i] = run; run += deg[i];
    }
    if (t == 0) rowptr[n] = Etot;
}

__global__ void fill_kernel(const int* __restrict__ src, const int* __restrict__ dst,
                            int* __restrict__ cursor, int* __restrict__ col, int E) {
    int e = blockIdx.x * blockDim.x + threadIdx.x;
    if (e < E) {
        int d = dst[e];
        int p = atomicAdd(&cursor[d], 1);
        col[p] = src[e];
    }
}

// ---------- weight transpose+convert ----------
__global__ __launch_bounds__(256) void wtrans_kernel(const float* __restrict__ Wm,
                                                     const float* __restrict__ Wu,
                                                     unsigned short* __restrict__ WtM,
                                                     unsigned short* __restrict__ WtU) {
    int mat = blockIdx.z;
    const float* src = (mat < HOPS) ? (Wm + (size_t)mat * 512 * 256)
                                    : (Wu + (size_t)(mat - HOPS) * 512 * 256);
    unsigned short* dstp = (mat < HOPS) ? (WtM + (size_t)mat * 256 * 512)
                                        : (WtU + (size_t)(mat - HOPS) * 256 * 512);
    int k0 = blockIdx.x * 32, n0 = blockIdx.y * 32;
    __shared__ float T[32][33];
    int tr = threadIdx.x >> 5, tc = threadIdx.x & 31;
#pragma unroll
    for (int r = 0; r < 4; ++r) {
        int k = tr + r * 8;
        T[tc][k] = src[(size_t)(k0 + k) * 256 + n0 + tc];
    }
    __syncthreads();
#pragma unroll
    for (int r = 0; r < 4; ++r) {
        int nn = tr + r * 8;
        dstp[(size_t)(n0 + nn) * 512 + k0 + tc] = f2b(T[nn][tc]);
    }
}

// ---------- initial projection ----------
__global__ void init_h_kernel(const float* __restrict__ nodes,
                              const int* __restrict__ node_types,
                              const float* __restrict__ type_emb,
                              const float* __restrict__ W_proj,
                              const float* __restrict__ b_proj,
                              unsigned short* __restrict__ h, int n) {
    int v = blockIdx.x;
    int t = threadIdx.x;
    __shared__ float sn[FDIM];
    if (t < FDIM) sn[t] = nodes[v * FDIM + t];
    __syncthreads();
    int ty = node_types[v];
    float acc = b_proj[t] + type_emb[ty * NDIM + t];
#pragma unroll
    for (int k = 0; k < FDIM; ++k) acc += sn[k] * W_proj[k * NDIM + t];
    h[(size_t)v * NDIM + t] = f2b(acc);
}

// ---------- neighbor sum ----------
__global__ __launch_bounds__(256) void agg_kernel(const unsigned short* __restrict__ h,
                                                  const int* __restrict__ rowptr,
                                                  const int* __restrict__ col,
                                                  unsigned short* __restrict__ S, int n) {
    int wv = threadIdx.x >> 6, lane = threadIdx.x & 63;
    int v = blockIdx.x * 4 + wv;
    if (v >= n) return;
    int beg = rowptr[v], end = rowptr[v + 1];
    float a0 = 0.f, a1 = 0.f, a2 = 0.f, a3 = 0.f;
    size_t lofs = (size_t)lane * 4;
    int i = beg;
    for (; i + 4 <= end; i += 4) {
        int c0 = col[i], c1 = col[i + 1], c2 = col[i + 2], c3 = col[i + 3];
        ushort4 x0 = *(const ushort4*)&h[(size_t)c0 * NDIM + lofs];
        ushort4 x1 = *(const ushort4*)&h[(size_t)c1 * NDIM + lofs];
        ushort4 x2 = *(const ushort4*)&h[(size_t)c2 * NDIM + lofs];
        ushort4 x3 = *(const ushort4*)&h[(size_t)c3 * NDIM + lofs];
        a0 += b2f(x0.x) + b2f(x1.x) + b2f(x2.x) + b2f(x3.x);
        a1 += b2f(x0.y) + b2f(x1.y) + b2f(x2.y) + b2f(x3.y);
        a2 += b2f(x0.z) + b2f(x1.z) + b2f(x2.z) + b2f(x3.z);
        a3 += b2f(x0.w) + b2f(x1.w) + b2f(x2.w) + b2f(x3.w);
    }
    for (; i < end; ++i) {
        int c = col[i];
        ushort4 x = *(const ushort4*)&h[(size_t)c * NDIM + lofs];
        a0 += b2f(x.x); a1 += b2f(x.y); a2 += b2f(x.z); a3 += b2f(x.w);
    }
    ushort4 o; o.x = f2b(a0); o.y = f2b(a1); o.z = f2b(a2); o.w = f2b(a3);
    *(ushort4*)&S[(size_t)v * NDIM + lofs] = o;
}

// ---------- MFMA GEMM ----------
#define BM 128
#define BN 128
#define BK 32
#define ASTR (BK + 8)

template <bool RELU, bool SCALEY>
__global__ __launch_bounds__(256) void gemm_kernel(const unsigned short* __restrict__ X,
                                                   const unsigned short* __restrict__ Y,
                                                   const int* __restrict__ deg,
                                                   const unsigned short* __restrict__ Wt,
                                                   const float* __restrict__ bias,
                                                   unsigned short* __restrict__ Out, int n) {
    __shared__ unsigned short As[BM][ASTR];
    __shared__ unsigned short Bs[BN][ASTR];
    int t = threadIdx.x;
    int lane = t & 63;
    int w = t >> 6;
    int wm = w >> 1, wn = w & 1;
    int quad = lane >> 4, l16 = lane & 15;
    int row0 = blockIdx.x * BM;
    int n0 = blockIdx.y * BN;

    f32x4 acc[4][4];
#pragma unroll
    for (int i = 0; i < 4; ++i)
#pragma unroll
        for (int j = 0; j < 4; ++j) acc[i][j] = (f32x4)(0.f);

    for (int k0 = 0; k0 < 2 * NDIM; k0 += BK) {
        const unsigned short* P = (k0 < NDIM) ? X : Y;
        int kofs = k0 & (NDIM - 1);
        __syncthreads();
#pragma unroll
        for (int h2 = 0; h2 < 2; ++h2) {
            int c = t + h2 * 256;
            int r = c >> 2;
            int ko = (c & 3) * 8;
            int grow = row0 + r; if (grow >= n) grow = n - 1;
            uint4 u = *(const uint4*)(P + (size_t)grow * NDIM + kofs + ko);
            if (SCALEY && k0 >= NDIM) {
                float s = (float)deg[grow];
                unsigned short* up = (unsigned short*)&u;
#pragma unroll
                for (int j = 0; j < 8; ++j) up[j] = f2b(b2f(up[j]) * s);
            }
            *(uint4*)&As[r][ko] = u;
        }
#pragma unroll
        for (int h2 = 0; h2 < 2; ++h2) {
            int c = t + h2 * 256;
            int r = c >> 2;
            int ko = (c & 3) * 8;
            uint4 u = *(const uint4*)(Wt + (size_t)(n0 + r) * 512 + k0 + ko);
            *(uint4*)&Bs[r][ko] = u;
        }
        __syncthreads();
        short8 af[4], bf[4];
#pragma unroll
        for (int mt = 0; mt < 4; ++mt)
            af[mt] = *(const short8*)&As[wm * 64 + mt * 16 + l16][quad * 8];
#pragma unroll
        for (int nt = 0; nt < 4; ++nt)
            bf[nt] = *(const short8*)&Bs[wn * 64 + nt * 16 + l16][quad * 8];
#pragma unroll
        for (int mt = 0; mt < 4; ++mt)
#pragma unroll
            for (int nt = 0; nt < 4; ++nt)
                acc[mt][nt] = __builtin_amdgcn_mfma_f32_16x16x32_bf16(af[mt], bf[nt], acc[mt][nt], 0, 0, 0);
    }
#pragma unroll
    for (int mt = 0; mt < 4; ++mt) {
#pragma unroll
        for (int nt = 0; nt < 4; ++nt) {
            int col = n0 + wn * 64 + nt * 16 + l16;
            float bcol = bias[col];
#pragma unroll
            for (int r = 0; r < 4; ++r) {
                int row = row0 + wm * 64 + mt * 16 + quad * 4 + r;
                if (row < n) {
                    float bm = SCALEY ? (float)deg[row] : 1.0f;
                    float v = acc[mt][nt][r] + bm * bcol;
                    if (RELU) v = fmaxf(v, 0.f);
                    Out[(size_t)row * NDIM + col] = f2b(v);
                }
            }
        }
    }
}

// ---------- column max over nodes: ushort4-wide, 4 row-streams/block ----------
__global__ __launch_bounds__(256) void colmax_kernel(const unsigned short* __restrict__ h,
                                                     float* __restrict__ partial, int n) {
    __shared__ float red[4][NDIM];
    int t = threadIdx.x;
    int lane = t & 63, w = t >> 6;
    int c0 = lane * 4;
    float m0 = -1e30f, m1 = -1e30f, m2 = -1e30f, m3 = -1e30f;
#pragma unroll 4
    for (int v = blockIdx.x * 4 + w; v < n; v += gridDim.x * 4) {
        ushort4 x = *(const ushort4*)&h[(size_t)v * NDIM + c0];
        m0 = fmaxf(m0, b2f(x.x)); m1 = fmaxf(m1, b2f(x.y));
        m2 = fmaxf(m2, b2f(x.z)); m3 = fmaxf(m3, b2f(x.w));
    }
    red[w][c0 + 0] = m0; red[w][c0 + 1] = m1;
    red[w][c0 + 2] = m2; red[w][c0 + 3] = m3;
    __syncthreads();
    float m = fmaxf(fmaxf(red[0][t], red[1][t]), fmaxf(red[2][t], red[3][t]));
    partial[blockIdx.x * NDIM + t] = m;
}

// ---------- final: ge = colmax(partial); out = ge @ W_out + b_out ----------
__global__ __launch_bounds__(1024) void out_kernel(const float* __restrict__ partial, int nb,
                                                   const float* __restrict__ W_out,
                                                   const float* __restrict__ b_out,
                                                   float* __restrict__ out) {
    __shared__ float ge[NDIM];
    __shared__ float red[4][NDIM];
    int t = threadIdx.x & 255;   // column
    int g = threadIdx.x >> 8;    // group 0..3
    float m = -1e30f;
#pragma unroll 8
    for (int b = g; b < nb; b += 4)
        m = fmaxf(m, partial[b * NDIM + t]);
    red[g][t] = m;
    __syncthreads();
    if (g == 0)
        ge[t] = fmaxf(fmaxf(red[0][t], red[1][t]), fmaxf(red[2][t], red[3][t]));
    __syncthreads();
    float acc = 0.f;
#pragma unroll 8
    for (int kk = 0; kk < 64; ++kk) {
        int k = g * 64 + kk;
        acc += ge[k] * W_out[k * NDIM + t];
    }
    red[g][t] = acc;
    __syncthreads();
    if (g == 0)
        out[t] = b_out[t] + red[0][t] + red[1][t] + red[2][t] + red[3][t];
}

// ---------- launch ----------
extern "C" void kernel_launch(void* const* d_in, const int* in_sizes, int n_in,
                              void* d_out, int out_size, void* d_ws, size_t ws_size,
                              hipStream_t stream) {
    const float* nodes      = (const float*)d_in[0];
    const int*   edges      = (const int*)d_in[1];
    const int*   node_types = (const int*)d_in[2];
    const float* type_emb   = (const float*)d_in[3];
    const float* W_proj     = (const float*)d_in[4];
    const float* b_proj     = (const float*)d_in[5];
    const float* W_msg      = (const float*)d_in[6];
    const float* b_msg      = (const float*)d_in[7];
    const float* W_upd      = (const float*)d_in[8];
    const float* b_upd      = (const float*)d_in[9];
    const float* W_out      = (const float*)d_in[10];
    const float* b_out      = (const float*)d_in[11];

    int n = in_sizes[2];
    int E = in_sizes[1] / 2;
    const int* src = edges;
    const int* dst = edges + E;

    size_t off = 0;
    auto alloc = [&](size_t bytes) {
        void* p = (char*)d_ws + off;
        off += (bytes + 255) & ~(size_t)255;
        return p;
    };
    int* deg    = (int*)alloc((size_t)n * 4);
    int* rowptr = (int*)alloc((size_t)(n + 1) * 4);
    int* cursor = (int*)alloc((size_t)n * 4);
    int* col    = (int*)alloc((size_t)E * 4);
    unsigned short* WtM = (unsigned short*)alloc((size_t)HOPS * 256 * 512 * 2);
    unsigned short* WtU = (unsigned short*)alloc((size_t)HOPS * 256 * 512 * 2);
    unsigned short* hA  = (unsigned short*)alloc((size_t)n * NDIM * 2);
    unsigned short* hB  = (unsigned short*)alloc((size_t)n * NDIM * 2);
    unsigned short* hC  = (unsigned short*)alloc((size_t)n * NDIM * 2);
    float* partial = (float*)alloc((size_t)256 * NDIM * 4);

    hipMemsetAsync(deg, 0, (size_t)n * 4, stream);
    int eb = (E + 255) / 256;
    hist_kernel<<<eb, 256, 0, stream>>>(dst, deg, E);
    scan_kernel<<<1, 1024, 0, stream>>>(deg, rowptr, cursor, n, E);
    fill_kernel<<<eb, 256, 0, stream>>>(src, dst, cursor, col, E);
    dim3 wg(512 / 32, 256 / 32, 2 * HOPS);
    wtrans_kernel<<<wg, 256, 0, stream>>>(W_msg, W_upd, WtM, WtU);
    init_h_kernel<<<n, 256, 0, stream>>>(nodes, node_types, type_emb, W_proj, b_proj, hA, n);

    unsigned short* h  = hA;
    unsigned short* Sb = hB;
    unsigned short* Ab = hC;
    int gx = (n + BM - 1) / BM;
    dim3 ggrid(gx, NDIM / BN);
    for (int i = 0; i < HOPS; ++i) {
        agg_kernel<<<(n + 3) / 4, 256, 0, stream>>>(h, rowptr, col, Sb, n);
        gemm_kernel<false, true><<<ggrid, 256, 0, stream>>>(
            Sb, h, deg, WtM + (size_t)i * 256 * 512, b_msg + (size_t)i * NDIM, Ab, n);
        gemm_kernel<true, false><<<ggrid, 256, 0, stream>>>(
            h, Ab, deg, WtU + (size_t)i * 256 * 512, b_upd + (size_t)i * NDIM, Sb, n);
        unsigned short* tmp = h; h = Sb; Sb = tmp;
    }
    colmax_kernel<<<256, 256, 0, stream>>>(h, partial, n);
    out_kernel<<<1, 1024, 0, stream>>>(partial, 256, W_out, b_out, (float*)d_out);
}

// Round 6
// 496.475 us; speedup vs baseline: 2.8051x; 1.1110x over previous
//
#include <hip/hip_runtime.h>
#include <hip/hip_bf16.h>

#define NDIM 256
#define FDIM 32
#define HOPS 4
#define KTOT 768   // [S ; h ; deg*h]

typedef __attribute__((ext_vector_type(8))) short short8;
typedef __attribute__((ext_vector_type(4))) float f32x4;

// ---------- helpers ----------
__device__ inline float b2f(unsigned short u) {
    union { unsigned int i; float f; } v; v.i = ((unsigned int)u) << 16; return v.f;
}
__device__ inline unsigned short f2b(float f) {
    union { float f; unsigned int i; } v; v.f = f;
    unsigned int r = v.i + 0x7FFF + ((v.i >> 16) & 1);
    return (unsigned short)(r >> 16);
}

// ---------- CSR build ----------
__global__ void hist_kernel(const int* __restrict__ dst, int* __restrict__ deg, int E) {
    int e = blockIdx.x * blockDim.x + threadIdx.x;
    if (e < E) atomicAdd(&deg[dst[e]], 1);
}

__global__ __launch_bounds__(1024) void scan_kernel(const int* __restrict__ deg,
                                                    int* __restrict__ rowptr,
                                                    int* __restrict__ cursor, int n, int Etot) {
    __shared__ int wsum[16];
    int t = threadIdx.x;
    int per = (n + 1023) / 1024;
    int lo = t * per; if (lo > n) lo = n;
    int hi = lo + per; if (hi > n) hi = n;
    int s = 0;
    for (int i = lo; i < hi; ++i) s += deg[i];
    int lane = t & 63, wid = t >> 6;
    int v = s;
#pragma unroll
    for (int d = 1; d < 64; d <<= 1) {
        int u = __shfl_up(v, d, 64);
        if (lane >= d) v += u;
    }
    if (lane == 63) wsum[wid] = v;
    __syncthreads();
    if (wid == 0) {
        int ws = (lane < 16) ? wsum[lane] : 0;
#pragma unroll
        for (int d = 1; d < 16; d <<= 1) {
            int u = __shfl_up(ws, d, 64);
            if (lane >= d) ws += u;
        }
        if (lane < 16) wsum[lane] = ws;
    }
    __syncthreads();
    int base = (wid > 0 ? wsum[wid - 1] : 0) + (v - s);
    int run = base;
    for (int i = lo; i < hi; ++i) {
        rowptr[i] = run; cursor[i] = run; run += deg[i];
    }
    if (t == 0) rowptr[n] = Etot;
}

__global__ void fill_kernel(const int* __restrict__ src, const int* __restrict__ dst,
                            int* __restrict__ cursor, int* __restrict__ col, int E) {
    int e = blockIdx.x * blockDim.x + threadIdx.x;
    if (e < E) {
        int d = dst[e];
        int p = atomicAdd(&cursor[d], 1);
        col[p] = src[e];
    }
}

// ---------- Wu1 transpose: Wt[hop][nn][256+k] = W_upd[hop][k][nn], k in 0..255 ----------
__global__ __launch_bounds__(256) void wtrans_u1_kernel(const float* __restrict__ Wu,
                                                        unsigned short* __restrict__ Wt) {
    int hop = blockIdx.z;
    const float* src = Wu + (size_t)hop * 512 * 256;
    unsigned short* dstp = Wt + (size_t)hop * 256 * KTOT;
    int k0 = blockIdx.x * 32, n0 = blockIdx.y * 32;
    __shared__ float T[32][33];
    int tr = threadIdx.x >> 5, tc = threadIdx.x & 31;
#pragma unroll
    for (int r = 0; r < 4; ++r) {
        int k = tr + r * 8;
        T[tc][k] = src[(size_t)(k0 + k) * 256 + n0 + tc];
    }
    __syncthreads();
#pragma unroll
    for (int r = 0; r < 4; ++r) {
        int nn = tr + r * 8;
        dstp[(size_t)(n0 + nn) * KTOT + 256 + k0 + tc] = f2b(T[nn][tc]);
    }
}

// ---------- M1/M2 precompute: M = Wm_half @ Wu2, stored transposed in Wt ----------
// blockIdx.z = hop*2 + which (which 0: M1 (k base 0), 1: M2 (k base 512))
__global__ __launch_bounds__(256) void mm_kernel(const float* __restrict__ Wm,
                                                 const float* __restrict__ Wu,
                                                 unsigned short* __restrict__ Wt) {
    int m = blockIdx.z;
    int hop = m >> 1, which = m & 1;
    const float* A = Wm + (size_t)hop * 512 * 256 + (size_t)which * 256 * 256; // rows k: A[k][j]
    const float* B = Wu + (size_t)hop * 512 * 256 + (size_t)256 * 256;         // rows j: B[j][nc]
    unsigned short* W = Wt + (size_t)hop * 256 * KTOT;
    int kbase = which ? 512 : 0;
    int k0 = blockIdx.x * 64, n0 = blockIdx.y * 64;
    __shared__ float As[32][68];  // As[jj][kk] = A[k0+kk][j0+jj]
    __shared__ float Bs[32][68];  // Bs[jj][nn] = B[j0+jj][n0+nn]
    int t = threadIdx.x;
    int tx = t & 15, ty = t >> 4;
    float acc[4][4];
#pragma unroll
    for (int a = 0; a < 4; ++a)
#pragma unroll
        for (int b = 0; b < 4; ++b) acc[a][b] = 0.f;

    for (int j0 = 0; j0 < 256; j0 += 32) {
        __syncthreads();
#pragma unroll
        for (int c = 0; c < 2; ++c) {
            int idx = t + c * 256;
            int kk = idx >> 3;          // 0..63
            int jj = (idx & 7) * 4;     // 0..28
            float4 va = *(const float4*)&A[(size_t)(k0 + kk) * 256 + j0 + jj];
            As[jj + 0][kk] = va.x; As[jj + 1][kk] = va.y;
            As[jj + 2][kk] = va.z; As[jj + 3][kk] = va.w;
            int jj2 = idx >> 4;         // 0..31
            int nn = (idx & 15) * 4;    // 0..60
            float4 vb = *(const float4*)&B[(size_t)(j0 + jj2) * 256 + n0 + nn];
            *(float4*)&Bs[jj2][nn] = vb;
        }
        __syncthreads();
#pragma unroll
        for (int jj = 0; jj < 32; ++jj) {
            float av[4];
#pragma unroll
            for (int a = 0; a < 4; ++a) av[a] = As[jj][ty * 4 + a];
            float4 bv = *(const float4*)&Bs[jj][tx * 4];
#pragma unroll
            for (int a = 0; a < 4; ++a) {
                acc[a][0] += av[a] * bv.x; acc[a][1] += av[a] * bv.y;
                acc[a][2] += av[a] * bv.z; acc[a][3] += av[a] * bv.w;
            }
        }
    }
    // write transposed: Wt[nn][kbase + k], 4 k-contiguous per nn
#pragma unroll
    for (int b = 0; b < 4; ++b) {
        int nn = n0 + tx * 4 + b;
        ushort4 o;
        o.x = f2b(acc[0][b]); o.y = f2b(acc[1][b]);
        o.z = f2b(acc[2][b]); o.w = f2b(acc[3][b]);
        *(ushort4*)&W[(size_t)nn * KTOT + kbase + k0 + ty * 4] = o;
    }
}

// ---------- cvec[hop] = b_msg[hop] @ Wu2[hop] ----------
__global__ __launch_bounds__(256) void cvec_kernel(const float* __restrict__ bm,
                                                   const float* __restrict__ Wu,
                                                   float* __restrict__ cvec) {
    int hop = blockIdx.x;
    int t = threadIdx.x;
    __shared__ float sb[256];
    sb[t] = bm[hop * 256 + t];
    __syncthreads();
    const float* B = Wu + (size_t)hop * 512 * 256 + (size_t)256 * 256;
    float acc = 0.f;
#pragma unroll 8
    for (int j = 0; j < 256; ++j) acc += sb[j] * B[(size_t)j * 256 + t];
    cvec[hop * 256 + t] = acc;
}

// ---------- initial projection ----------
__global__ void init_h_kernel(const float* __restrict__ nodes,
                              const int* __restrict__ node_types,
                              const float* __restrict__ type_emb,
                              const float* __restrict__ W_proj,
                              const float* __restrict__ b_proj,
                              unsigned short* __restrict__ h, int n) {
    int v = blockIdx.x;
    int t = threadIdx.x;
    __shared__ float sn[FDIM];
    if (t < FDIM) sn[t] = nodes[v * FDIM + t];
    __syncthreads();
    int ty = node_types[v];
    float acc = b_proj[t] + type_emb[ty * NDIM + t];
#pragma unroll
    for (int k = 0; k < FDIM; ++k) acc += sn[k] * W_proj[k * NDIM + t];
    h[(size_t)v * NDIM + t] = f2b(acc);
}

// ---------- neighbor sum ----------
__global__ __launch_bounds__(256) void agg_kernel(const unsigned short* __restrict__ h,
                                                  const int* __restrict__ rowptr,
                                                  const int* __restrict__ col,
                                                  unsigned short* __restrict__ S, int n) {
    int wv = threadIdx.x >> 6, lane = threadIdx.x & 63;
    int v = blockIdx.x * 4 + wv;
    if (v >= n) return;
    int beg = rowptr[v], end = rowptr[v + 1];
    float a0 = 0.f, a1 = 0.f, a2 = 0.f, a3 = 0.f;
    size_t lofs = (size_t)lane * 4;
    int i = beg;
    for (; i + 4 <= end; i += 4) {
        int c0 = col[i], c1 = col[i + 1], c2 = col[i + 2], c3 = col[i + 3];
        ushort4 x0 = *(const ushort4*)&h[(size_t)c0 * NDIM + lofs];
        ushort4 x1 = *(const ushort4*)&h[(size_t)c1 * NDIM + lofs];
        ushort4 x2 = *(const ushort4*)&h[(size_t)c2 * NDIM + lofs];
        ushort4 x3 = *(const ushort4*)&h[(size_t)c3 * NDIM + lofs];
        a0 += b2f(x0.x) + b2f(x1.x) + b2f(x2.x) + b2f(x3.x);
        a1 += b2f(x0.y) + b2f(x1.y) + b2f(x2.y) + b2f(x3.y);
        a2 += b2f(x0.z) + b2f(x1.z) + b2f(x2.z) + b2f(x3.z);
        a3 += b2f(x0.w) + b2f(x1.w) + b2f(x2.w) + b2f(x3.w);
    }
    for (; i < end; ++i) {
        int c = col[i];
        ushort4 x = *(const ushort4*)&h[(size_t)c * NDIM + lofs];
        a0 += b2f(x.x); a1 += b2f(x.y); a2 += b2f(x.z); a3 += b2f(x.w);
    }
    ushort4 o; o.x = f2b(a0); o.y = f2b(a1); o.z = f2b(a2); o.w = f2b(a3);
    *(ushort4*)&S[(size_t)v * NDIM + lofs] = o;
}

// ---------- fused hop GEMM: h' = relu([S ; h ; deg*h] @ Wt^T + b_upd + deg*cvec) ----------
// Wt is [256][768] bf16. LAST: also column-max into geInt via atomics.
#define BM 128
#define BN 128
#define BK 32
#define ASTR (BK + 8)

template <bool LAST>
__global__ __launch_bounds__(256) void gemm_hop_kernel(const unsigned short* __restrict__ S,
                                                       const unsigned short* __restrict__ hcur,
                                                       const int* __restrict__ deg,
                                                       const unsigned short* __restrict__ Wt,
                                                       const float* __restrict__ bupd,
                                                       const float* __restrict__ cvec,
                                                       unsigned short* __restrict__ Out,
                                                       int* __restrict__ geInt, int n) {
    __shared__ unsigned short As[BM][ASTR];
    __shared__ unsigned short Bs[BN][ASTR];
    __shared__ int smax[BN];
    int t = threadIdx.x;
    int lane = t & 63;
    int w = t >> 6;
    int wm = w >> 1, wn = w & 1;
    int quad = lane >> 4, l16 = lane & 15;
    int row0 = blockIdx.x * BM;
    int n0 = blockIdx.y * BN;

    if (LAST) {
        if (t < BN) smax[t] = 0;
    }

    f32x4 acc[4][4];
#pragma unroll
    for (int i = 0; i < 4; ++i)
#pragma unroll
        for (int j = 0; j < 4; ++j) acc[i][j] = (f32x4)(0.f);

    for (int k0 = 0; k0 < KTOT; k0 += BK) {
        const unsigned short* P = (k0 < NDIM) ? S : hcur;
        int kofs = (k0 < NDIM) ? k0 : ((k0 < 2 * NDIM) ? k0 - NDIM : k0 - 2 * NDIM);
        bool scale = (k0 >= 2 * NDIM);
        __syncthreads();
#pragma unroll
        for (int h2 = 0; h2 < 2; ++h2) {
            int c = t + h2 * 256;
            int r = c >> 2;
            int ko = (c & 3) * 8;
            int grow = row0 + r; if (grow >= n) grow = n - 1;
            uint4 u = *(const uint4*)(P + (size_t)grow * NDIM + kofs + ko);
            if (scale) {
                float s = (float)deg[grow];
                unsigned short* up = (unsigned short*)&u;
#pragma unroll
                for (int j = 0; j < 8; ++j) up[j] = f2b(b2f(up[j]) * s);
            }
            *(uint4*)&As[r][ko] = u;
        }
#pragma unroll
        for (int h2 = 0; h2 < 2; ++h2) {
            int c = t + h2 * 256;
            int r = c >> 2;
            int ko = (c & 3) * 8;
            uint4 u = *(const uint4*)(Wt + (size_t)(n0 + r) * KTOT + k0 + ko);
            *(uint4*)&Bs[r][ko] = u;
        }
        __syncthreads();
        short8 af[4], bf[4];
#pragma unroll
        for (int mt = 0; mt < 4; ++mt)
            af[mt] = *(const short8*)&As[wm * 64 + mt * 16 + l16][quad * 8];
#pragma unroll
        for (int nt = 0; nt < 4; ++nt)
            bf[nt] = *(const short8*)&Bs[wn * 64 + nt * 16 + l16][quad * 8];
#pragma unroll
        for (int mt = 0; mt < 4; ++mt)
#pragma unroll
            for (int nt = 0; nt < 4; ++nt)
                acc[mt][nt] = __builtin_amdgcn_mfma_f32_16x16x32_bf16(af[mt], bf[nt], acc[mt][nt], 0, 0, 0);
    }
    // epilogue: C/D layout col=lane&15, row=quad*4+reg
#pragma unroll
    for (int mt = 0; mt < 4; ++mt) {
#pragma unroll
        for (int nt = 0; nt < 4; ++nt) {
            int lcol = wn * 64 + nt * 16 + l16;
            int col = n0 + lcol;
            float bu = bupd[col];
            float cv = cvec[col];
            float cmax = 0.f;
#pragma unroll
            for (int r = 0; r < 4; ++r) {
                int row = row0 + wm * 64 + mt * 16 + quad * 4 + r;
                if (row < n) {
                    float dg = (float)deg[row];
                    float v = fmaxf(acc[mt][nt][r] + bu + dg * cv, 0.f);
                    Out[(size_t)row * NDIM + col] = f2b(v);
                    if (LAST) cmax = fmaxf(cmax, v);
                }
            }
            if (LAST) atomicMax(&smax[lcol], __float_as_int(cmax));
        }
    }
    if (LAST) {
        __syncthreads();
        if (t < BN) atomicMax(&geInt[n0 + t], smax[t]);
    }
}

// ---------- final: out = ge @ W_out + b_out ----------
__global__ __launch_bounds__(1024) void out_kernel(const float* __restrict__ ge,
                                                   const float* __restrict__ W_out,
                                                   const float* __restrict__ b_out,
                                                   float* __restrict__ out) {
    __shared__ float red[4][NDIM];
    int t = threadIdx.x & 255;
    int g = threadIdx.x >> 8;
    float acc = 0.f;
#pragma unroll 8
    for (int kk = 0; kk < 64; ++kk) {
        int k = g * 64 + kk;
        acc += ge[k] * W_out[k * NDIM + t];
    }
    red[g][t] = acc;
    __syncthreads();
    if (g == 0)
        out[t] = b_out[t] + red[0][t] + red[1][t] + red[2][t] + red[3][t];
}

// ---------- launch ----------
extern "C" void kernel_launch(void* const* d_in, const int* in_sizes, int n_in,
                              void* d_out, int out_size, void* d_ws, size_t ws_size,
                              hipStream_t stream) {
    const float* nodes      = (const float*)d_in[0];
    const int*   edges      = (const int*)d_in[1];
    const int*   node_types = (const int*)d_in[2];
    const float* type_emb   = (const float*)d_in[3];
    const float* W_proj     = (const float*)d_in[4];
    const float* b_proj     = (const float*)d_in[5];
    const float* W_msg      = (const float*)d_in[6];
    const float* b_msg      = (const float*)d_in[7];
    const float* W_upd      = (const float*)d_in[8];
    const float* b_upd      = (const float*)d_in[9];
    const float* W_out      = (const float*)d_in[10];
    const float* b_out      = (const float*)d_in[11];

    int n = in_sizes[2];
    int E = in_sizes[1] / 2;
    const int* src = edges;
    const int* dst = edges + E;

    size_t off = 0;
    auto alloc = [&](size_t bytes) {
        void* p = (char*)d_ws + off;
        off += (bytes + 255) & ~(size_t)255;
        return p;
    };
    int* deg    = (int*)alloc((size_t)n * 4);
    int* rowptr = (int*)alloc((size_t)(n + 1) * 4);
    int* cursor = (int*)alloc((size_t)n * 4);
    int* col    = (int*)alloc((size_t)E * 4);
    unsigned short* Wt = (unsigned short*)alloc((size_t)HOPS * 256 * KTOT * 2);
    float* cvec = (float*)alloc((size_t)HOPS * 256 * 4);
    int* geInt  = (int*)alloc((size_t)256 * 4);
    unsigned short* hA  = (unsigned short*)alloc((size_t)n * NDIM * 2);
    unsigned short* hB  = (unsigned short*)alloc((size_t)n * NDIM * 2);
    unsigned short* Sb  = (unsigned short*)alloc((size_t)n * NDIM * 2);

    hipMemsetAsync(deg, 0, (size_t)n * 4, stream);
    hipMemsetAsync(geInt, 0, 256 * 4, stream);
    int eb = (E + 255) / 256;
    hist_kernel<<<eb, 256, 0, stream>>>(dst, deg, E);
    scan_kernel<<<1, 1024, 0, stream>>>(deg, rowptr, cursor, n, E);
    fill_kernel<<<eb, 256, 0, stream>>>(src, dst, cursor, col, E);
    wtrans_u1_kernel<<<dim3(8, 8, HOPS), 256, 0, stream>>>(W_upd, Wt);
    mm_kernel<<<dim3(4, 4, 2 * HOPS), 256, 0, stream>>>(W_msg, W_upd, Wt);
    cvec_kernel<<<HOPS, 256, 0, stream>>>(b_msg, W_upd, cvec);
    init_h_kernel<<<n, 256, 0, stream>>>(nodes, node_types, type_emb, W_proj, b_proj, hA, n);

    unsigned short* h  = hA;
    unsigned short* ho = hB;
    int gx = (n + BM - 1) / BM;
    dim3 ggrid(gx, NDIM / BN);
    for (int i = 0; i < HOPS; ++i) {
        agg_kernel<<<(n + 3) / 4, 256, 0, stream>>>(h, rowptr, col, Sb, n);
        if (i == HOPS - 1)
            gemm_hop_kernel<true><<<ggrid, 256, 0, stream>>>(
                Sb, h, deg, Wt + (size_t)i * 256 * KTOT, b_upd + (size_t)i * NDIM,
                cvec + (size_t)i * NDIM, ho, geInt, n);
        else
            gemm_hop_kernel<false><<<ggrid, 256, 0, stream>>>(
                Sb, h, deg, Wt + (size_t)i * 256 * KTOT, b_upd + (size_t)i * NDIM,
                cvec + (size_t)i * NDIM, ho, geInt, n);
        unsigned short* tmp = h; h = ho; ho = tmp;
    }
    out_kernel<<<1, 1024, 0, stream>>>((const float*)geInt, W_out, b_out, (float*)d_out);
}